// Round 1
// baseline (214.332 us; speedup 1.0000x reference)
//
#include <hip/hip_runtime.h>

// BatchRelationalModule: B=32, C=128, H=W=12 -> L=144, D=129, HID=64
// out[b,k] = MLP( sum_{i,j} leaky( leaky(gi[b,j,:]+gj[b,i,:]+b1) @ W2 + b2 )[k] )

#define B_   32
#define C_   128
#define L_   144
#define HID_ 64
#define D_   129
#define STR  65   // LDS row stride (+1 pad: (t+k)%32 bank spread, conflict-free)

// ---------------- kernel 1: gi/gj projection --------------------------------
// gi[b,l,h] = sum_c x[b,c,l]*W1[c,h] + l*W1[128,h]
// gj[b,l,h] = sum_c x[b,c,l]*W1[129+c,h] + l*W1[257,h]
__global__ __launch_bounds__(256) void k_proj(const float* __restrict__ x_img,
                                              const float* __restrict__ W1,
                                              float* __restrict__ gi,
                                              float* __restrict__ gj)
{
    int t   = threadIdx.x;
    int h   = t & 63;
    int sub = t >> 6;                 // wave index -> which l (uniform per wave)
    int bid = blockIdx.x;             // 0 .. B_*36-1
    int b   = bid / 36;
    int l   = (bid % 36) * 4 + sub;

    const float* Wa = W1;             // rows 0..128
    const float* Wb = W1 + D_ * HID_; // rows 129..257
    const float* xp = x_img + (size_t)(b * C_) * L_ + l;

    float ai = 0.f, aj = 0.f;
#pragma unroll 4
    for (int c = 0; c < C_; ++c) {
        float xv = xp[c * L_];        // wave-uniform -> scalar load
        ai = fmaf(xv, Wa[c * HID_ + h], ai);
        aj = fmaf(xv, Wb[c * HID_ + h], aj);
    }
    float fl = (float)l;              // coord feature (d = 128)
    ai = fmaf(fl, Wa[C_ * HID_ + h], ai);
    aj = fmaf(fl, Wb[C_ * HID_ + h], aj);

    int o = (b * L_ + l) * HID_ + h;
    gi[o] = ai;
    gj[o] = aj;
}

// ---------------- kernel 2: pairwise core -----------------------------------
// acc[b,k] += leaky( sum_h leaky(gi[j,h]+gjb[i,h]) * W2[h,k] + b2[k] ) over pairs
__global__ __launch_bounds__(256, 2) void k_pairs(const float* __restrict__ gi,
                                                  const float* __restrict__ gj,
                                                  const float* __restrict__ b1,
                                                  const float* __restrict__ W2,
                                                  const float* __restrict__ b2,
                                                  float* __restrict__ accum)
{
    __shared__ float smem[2 * L_ * STR];   // 74880 B -> 2 blocks/CU
    float* s_gi = smem;
    float* s_gj = smem + L_ * STR;

    int t = threadIdx.x;
    int b = blockIdx.x;

    // stage gi, gj (+b1 folded into gj) with +1 padded rows
    for (int idx = t; idx < L_ * HID_; idx += 256) {
        int l = idx >> 6, h = idx & 63;
        s_gi[l * STR + h] = gi[(size_t)b * (L_ * HID_) + idx];
        s_gj[l * STR + h] = gj[(size_t)b * (L_ * HID_) + idx] + b1[h];
    }
    __syncthreads();

    float acc[HID_];
#pragma unroll
    for (int k = 0; k < HID_; ++k) acc[k] = 0.f;

    // each lane owns one pair p = i*L_+j per iteration
    for (int p = blockIdx.y * 256 + t; p < L_ * L_; p += gridDim.y * 256) {
        int i = p / L_;
        int j = p - i * L_;
        const float* gr = &s_gi[j * STR];
        const float* hr = &s_gj[i * STR];

        float uu[HID_];
#pragma unroll
        for (int k = 0; k < HID_; ++k) uu[k] = 0.f;

        float a0 = gr[0], c0 = hr[0];
#pragma unroll 2
        for (int h = 0; h < HID_; ++h) {
            float a1 = gr[h + 1];      // h=63 reads pad element (in-bounds, unused)
            float c1 = hr[h + 1];
            float tv = a0 + c0;
            tv = fmaxf(tv, 0.01f * tv);            // leaky_relu
            const float* w2r = &W2[h * HID_];      // uniform -> s_load row
#pragma unroll
            for (int k = 0; k < HID_; ++k) uu[k] = fmaf(tv, w2r[k], uu[k]);
            a0 = a1; c0 = c1;
        }
#pragma unroll
        for (int k = 0; k < HID_; ++k) {
            float z = uu[k] + b2[k];
            acc[k] += fmaxf(z, 0.01f * z);         // leaky_relu
        }
    }

    // ---- block reduction: 256 lanes x 64 -> 64, via padded LDS transpose ----
    __syncthreads();                 // main-loop LDS reads done; reuse smem
    float* red = smem;               // needs 256*65 = 16640 floats <= 18720 ok
#pragma unroll
    for (int k = 0; k < HID_; ++k) red[t * STR + k] = acc[k];  // banks (t+k)%32: clean
    __syncthreads();

    int k = t & 63, q = t >> 6;      // 4 groups of 64 rows each
    float s = 0.f;
    for (int r = q * 64; r < q * 64 + 64; ++r) s += red[r * STR + k];
    atomicAdd(&accum[b * HID_ + k], s);
}

// ---------------- kernel 3: final 64->64->64 MLP ----------------------------
__global__ __launch_bounds__(64) void k_mlp(const float* __restrict__ accum,
                                            const float* __restrict__ Wp,
                                            const float* __restrict__ bp,
                                            const float* __restrict__ Wo,
                                            const float* __restrict__ bo,
                                            float* __restrict__ out)
{
    __shared__ float s0[HID_], s1[HID_];
    int b = blockIdx.x, k = threadIdx.x;
    s0[k] = accum[b * HID_ + k];
    __syncthreads();
    float v = bp[k];
#pragma unroll 8
    for (int h = 0; h < HID_; ++h) v = fmaf(s0[h], Wp[h * HID_ + k], v);
    v = fmaxf(v, 0.01f * v);
    s1[k] = v;
    __syncthreads();
    float w = bo[k];
#pragma unroll 8
    for (int h = 0; h < HID_; ++h) w = fmaf(s1[h], Wo[h * HID_ + k], w);
    w = fmaxf(w, 0.01f * w);
    out[b * HID_ + k] = w;
}

// ---------------- launch ----------------------------------------------------
extern "C" void kernel_launch(void* const* d_in, const int* in_sizes, int n_in,
                              void* d_out, int out_size, void* d_ws, size_t ws_size,
                              hipStream_t stream)
{
    const float* x_img = (const float*)d_in[0];
    const float* W1    = (const float*)d_in[1];
    const float* b1    = (const float*)d_in[2];
    const float* W2    = (const float*)d_in[3];
    const float* b2    = (const float*)d_in[4];
    const float* Wp    = (const float*)d_in[5];
    const float* bp    = (const float*)d_in[6];
    const float* Wo    = (const float*)d_in[7];
    const float* bo    = (const float*)d_in[8];
    float* out = (float*)d_out;

    float* gi    = (float*)d_ws;                 // B*L*HID = 294912 floats
    float* gj    = gi + B_ * L_ * HID_;          // 294912 floats
    float* accum = gj + B_ * L_ * HID_;          // B*HID = 2048 floats

    hipMemsetAsync(accum, 0, B_ * HID_ * sizeof(float), stream);

    k_proj <<<dim3(B_ * 36),  256, 0, stream>>>(x_img, W1, gi, gj);
    k_pairs<<<dim3(B_, 16),   256, 0, stream>>>(gi, gj, b1, W2, b2, accum);
    k_mlp  <<<dim3(B_),        64, 0, stream>>>(accum, Wp, bp, Wo, bo, out);
}

// Round 2
// 116.739 us; speedup vs baseline: 1.8360x; 1.8360x over previous
//
#include <hip/hip_runtime.h>

// BatchRelationalModule: B=32, C=128, H=W=12 -> L=144, D=129, HID=64
// out[b,k] = MLP( sum_{i,j} leaky( leaky(gi[b,j,:]+gj[b,i,:]+b1) @ W2 + b2 )[k] )
//
// Round 2: pairwise core reformulated as bf16 MFMA GEMM:
//   M = pairs (i,j), K = 64 (h), N = 64 (k); A built on the fly from LDS,
//   W2 held in registers as B-fragments, per-lane 4-float running sum.

#define B_   32
#define C_   128
#define L_   144
#define HID_ 64
#define D_   129
#define STR  65   // fp32 LDS row stride; A-build reads are <=2-way (free)

typedef __bf16 bf16x8 __attribute__((ext_vector_type(8)));
typedef float  floatx4 __attribute__((ext_vector_type(4)));

__device__ __forceinline__ float leaky(float x) { return fmaxf(x, 0.01f * x); }

// ---------------- kernel 1: gi/gj projection --------------------------------
__global__ __launch_bounds__(256) void k_proj(const float* __restrict__ x_img,
                                              const float* __restrict__ W1,
                                              float* __restrict__ gi,
                                              float* __restrict__ gj)
{
    int t   = threadIdx.x;
    int h   = t & 63;
    int sub = t >> 6;
    int bid = blockIdx.x;             // 0 .. B_*36-1
    int b   = bid / 36;
    int l   = (bid % 36) * 4 + sub;

    const float* Wa = W1;             // rows 0..128
    const float* Wb = W1 + D_ * HID_; // rows 129..257
    const float* xp = x_img + (size_t)(b * C_) * L_ + l;

    float ai = 0.f, aj = 0.f;
#pragma unroll 4
    for (int c = 0; c < C_; ++c) {
        float xv = xp[c * L_];        // wave-uniform -> scalar load
        ai = fmaf(xv, Wa[c * HID_ + h], ai);
        aj = fmaf(xv, Wb[c * HID_ + h], aj);
    }
    float fl = (float)l;
    ai = fmaf(fl, Wa[C_ * HID_ + h], ai);
    aj = fmaf(fl, Wb[C_ * HID_ + h], aj);

    int o = (b * L_ + l) * HID_ + h;
    gi[o] = ai;
    gj[o] = aj;
}

// ---------------- kernel 2: pairwise core via MFMA --------------------------
// grid = (B_, 18), 256 threads = 4 waves. Each wave: 2 i's x 9 j-tiles of 16.
__global__ __launch_bounds__(256, 2) void k_pairs(const float* __restrict__ gi,
                                                  const float* __restrict__ gj,
                                                  const float* __restrict__ b1,
                                                  const float* __restrict__ W2,
                                                  const float* __restrict__ b2,
                                                  float* __restrict__ accum)
{
    __shared__ float smem[2 * L_ * STR];   // 74880 B -> 2 blocks/CU
    float* s_gi  = smem;
    float* s_gjb = smem + L_ * STR;

    const int t    = threadIdx.x;
    const int wave = t >> 6;
    const int lane = t & 63;
    const int m    = lane & 15;        // A row / C col index
    const int quad = lane >> 4;        // k-subchunk selector
    const int b    = blockIdx.x;

    // ---- stage gi and gj(+b1) into padded LDS (2-way banks: free) ----------
    for (int idx = t; idx < L_ * HID_; idx += 256) {
        int l = idx >> 6, h = idx & 63;
        s_gi [l * STR + h] = gi[(size_t)b * (L_ * HID_) + idx];
        s_gjb[l * STR + h] = gj[(size_t)b * (L_ * HID_) + idx] + b1[h];
    }

    // ---- W2 -> B-fragments in registers (once per wave) --------------------
    // B[k=h][n]: lane holds n = nt*16 + m, k = kc*32 + quad*8 + j
    bf16x8 Bf[2][4];
#pragma unroll
    for (int kc = 0; kc < 2; ++kc)
#pragma unroll
        for (int nt = 0; nt < 4; ++nt)
#pragma unroll
            for (int j = 0; j < 8; ++j)
                Bf[kc][nt][j] = (__bf16)W2[(kc * 32 + quad * 8 + j) * HID_ + nt * 16 + m];

    float b2v[4];
#pragma unroll
    for (int nt = 0; nt < 4; ++nt) b2v[nt] = b2[nt * 16 + m];

    float sacc[4] = {0.f, 0.f, 0.f, 0.f};
    const int h0 = quad * 8;

    __syncthreads();

    // ---- main loop: 2 i's per wave, 9 j-tiles each --------------------------
#pragma unroll
    for (int ii = 0; ii < 2; ++ii) {
        const int i = (blockIdx.y * 4 + wave) * 2 + ii;   // 0..143

        // hoist gjb row i for this lane's h-set (broadcast reads)
        float gjA[8], gjB[8];
#pragma unroll
        for (int j = 0; j < 8; ++j) {
            gjA[j] = s_gjb[i * STR + h0 + j];
            gjB[j] = s_gjb[i * STR + 32 + h0 + j];
        }

        for (int jt = 0; jt < 9; ++jt) {
            const float* gr = &s_gi[(jt * 16 + m) * STR];

            bf16x8 A0, A1;
#pragma unroll
            for (int j = 0; j < 8; ++j) {
                float v0 = gr[h0 + j]      + gjA[j];
                float v1 = gr[32 + h0 + j] + gjB[j];
                A0[j] = (__bf16)leaky(v0);
                A1[j] = (__bf16)leaky(v1);
            }

            floatx4 Cf[4];
#pragma unroll
            for (int nt = 0; nt < 4; ++nt) {
                Cf[nt] = floatx4{0.f, 0.f, 0.f, 0.f};
                Cf[nt] = __builtin_amdgcn_mfma_f32_16x16x32_bf16(A0, Bf[0][nt], Cf[nt], 0, 0, 0);
                Cf[nt] = __builtin_amdgcn_mfma_f32_16x16x32_bf16(A1, Bf[1][nt], Cf[nt], 0, 0, 0);
            }

            // epilogue: leaky(C + b2), accumulate over the 4 pair-rows this lane holds
#pragma unroll
            for (int nt = 0; nt < 4; ++nt) {
#pragma unroll
                for (int r = 0; r < 4; ++r)
                    sacc[nt] += leaky(Cf[nt][r] + b2v[nt]);
            }
        }
    }

    // ---- reduce across the 4 quad-groups (same n, different pair-rows) -----
#pragma unroll
    for (int nt = 0; nt < 4; ++nt) {
        float s = sacc[nt];
        s += __shfl_xor(s, 16, 64);
        s += __shfl_xor(s, 32, 64);
        if (quad == 0)
            atomicAdd(&accum[b * HID_ + nt * 16 + m], s);
    }
}

// ---------------- kernel 3: final 64->64->64 MLP ----------------------------
__global__ __launch_bounds__(64) void k_mlp(const float* __restrict__ accum,
                                            const float* __restrict__ Wp,
                                            const float* __restrict__ bp,
                                            const float* __restrict__ Wo,
                                            const float* __restrict__ bo,
                                            float* __restrict__ out)
{
    __shared__ float s0[HID_], s1[HID_];
    int b = blockIdx.x, k = threadIdx.x;
    s0[k] = accum[b * HID_ + k];
    __syncthreads();
    float v = bp[k];
#pragma unroll 8
    for (int h = 0; h < HID_; ++h) v = fmaf(s0[h], Wp[h * HID_ + k], v);
    v = leaky(v);
    s1[k] = v;
    __syncthreads();
    float w = bo[k];
#pragma unroll 8
    for (int h = 0; h < HID_; ++h) w = fmaf(s1[h], Wo[h * HID_ + k], w);
    w = leaky(w);
    out[b * HID_ + k] = w;
}

// ---------------- launch ----------------------------------------------------
extern "C" void kernel_launch(void* const* d_in, const int* in_sizes, int n_in,
                              void* d_out, int out_size, void* d_ws, size_t ws_size,
                              hipStream_t stream)
{
    const float* x_img = (const float*)d_in[0];
    const float* W1    = (const float*)d_in[1];
    const float* b1    = (const float*)d_in[2];
    const float* W2    = (const float*)d_in[3];
    const float* b2    = (const float*)d_in[4];
    const float* Wp    = (const float*)d_in[5];
    const float* bp    = (const float*)d_in[6];
    const float* Wo    = (const float*)d_in[7];
    const float* bo    = (const float*)d_in[8];
    float* out = (float*)d_out;

    float* gi    = (float*)d_ws;                 // B*L*HID floats
    float* gj    = gi + B_ * L_ * HID_;
    float* accum = gj + B_ * L_ * HID_;          // B*HID floats

    hipMemsetAsync(accum, 0, B_ * HID_ * sizeof(float), stream);

    k_proj <<<dim3(B_ * 36), 256, 0, stream>>>(x_img, W1, gi, gj);
    k_pairs<<<dim3(B_, 18),  256, 0, stream>>>(gi, gj, b1, W2, b2, accum);
    k_mlp  <<<dim3(B_),       64, 0, stream>>>(accum, Wp, bp, Wo, bo, out);
}

// Round 3
// 114.294 us; speedup vs baseline: 1.8753x; 1.0214x over previous
//
#include <hip/hip_runtime.h>

// BatchRelationalModule: B=32, C=128, H=W=12 -> L=144, D=129, HID=64
// out[b,k] = MLP( sum_{i,j} leaky( leaky(gi[b,j,:]+gj[b,i,:]+b1) @ W2 + b2 )[k] )
//
// Round 3: drop memset + atomics. k_pairs writes per-(b,yblock) partial sums
// (deterministic, every slot written); k_mlp reduces the 18 partials in its
// prologue. Pairwise core stays bf16-MFMA (round 2: 214 -> 116.7 us).

#define B_   32
#define C_   128
#define L_   144
#define HID_ 64
#define D_   129
#define STR  65   // fp32 LDS row stride; A-build reads are <=2-way (free)
#define YB_  18   // k_pairs grid.y (i-tiles of 8)

typedef __bf16 bf16x8 __attribute__((ext_vector_type(8)));
typedef float  floatx4 __attribute__((ext_vector_type(4)));

__device__ __forceinline__ float leaky(float x) { return fmaxf(x, 0.01f * x); }

// ---------------- kernel 1: gi/gj projection --------------------------------
__global__ __launch_bounds__(256) void k_proj(const float* __restrict__ x_img,
                                              const float* __restrict__ W1,
                                              float* __restrict__ gi,
                                              float* __restrict__ gj)
{
    int t   = threadIdx.x;
    int h   = t & 63;
    int sub = t >> 6;
    int bid = blockIdx.x;             // 0 .. B_*36-1
    int b   = bid / 36;
    int l   = (bid % 36) * 4 + sub;

    const float* Wa = W1;             // rows 0..128
    const float* Wb = W1 + D_ * HID_; // rows 129..257
    const float* xp = x_img + (size_t)(b * C_) * L_ + l;

    float ai = 0.f, aj = 0.f;
#pragma unroll 4
    for (int c = 0; c < C_; ++c) {
        float xv = xp[c * L_];
        ai = fmaf(xv, Wa[c * HID_ + h], ai);
        aj = fmaf(xv, Wb[c * HID_ + h], aj);
    }
    float fl = (float)l;
    ai = fmaf(fl, Wa[C_ * HID_ + h], ai);
    aj = fmaf(fl, Wb[C_ * HID_ + h], aj);

    int o = (b * L_ + l) * HID_ + h;
    gi[o] = ai;
    gj[o] = aj;
}

// ---------------- kernel 2: pairwise core via MFMA --------------------------
// grid = (B_, YB_), 256 threads = 4 waves. Each wave: 2 i's x 9 j-tiles of 16.
// Writes partial[(b*YB_ + yb)*64 + k] -- no atomics, no pre-zeroing needed.
__global__ __launch_bounds__(256, 2) void k_pairs(const float* __restrict__ gi,
                                                  const float* __restrict__ gj,
                                                  const float* __restrict__ b1,
                                                  const float* __restrict__ W2,
                                                  const float* __restrict__ b2,
                                                  float* __restrict__ partial)
{
    __shared__ float smem[2 * L_ * STR];   // 74880 B -> 2 blocks/CU
    float* s_gi  = smem;
    float* s_gjb = smem + L_ * STR;

    const int t    = threadIdx.x;
    const int wave = t >> 6;
    const int lane = t & 63;
    const int m    = lane & 15;        // A row / C col index
    const int quad = lane >> 4;        // k-subchunk selector
    const int b    = blockIdx.x;

    // ---- stage gi and gj(+b1) into padded LDS; float4 on the global side ---
    {
        const floatx4* g4i = (const floatx4*)(gi + (size_t)b * (L_ * HID_));
        const floatx4* g4j = (const floatx4*)(gj + (size_t)b * (L_ * HID_));
        for (int idx = t; idx < L_ * HID_ / 4; idx += 256) {
            int l  = idx >> 4;             // 16 float4 per row
            int h4 = (idx & 15) * 4;
            floatx4 vi = g4i[idx];
            floatx4 vj = g4j[idx];
#pragma unroll
            for (int q = 0; q < 4; ++q) {
                s_gi [l * STR + h4 + q] = vi[q];
                s_gjb[l * STR + h4 + q] = vj[q] + b1[h4 + q];
            }
        }
    }

    // ---- W2 -> B-fragments in registers (once per wave) --------------------
    bf16x8 Bf[2][4];
#pragma unroll
    for (int kc = 0; kc < 2; ++kc)
#pragma unroll
        for (int nt = 0; nt < 4; ++nt)
#pragma unroll
            for (int j = 0; j < 8; ++j)
                Bf[kc][nt][j] = (__bf16)W2[(kc * 32 + quad * 8 + j) * HID_ + nt * 16 + m];

    float b2v[4];
#pragma unroll
    for (int nt = 0; nt < 4; ++nt) b2v[nt] = b2[nt * 16 + m];

    float sacc[4] = {0.f, 0.f, 0.f, 0.f};
    const int h0 = quad * 8;

    __syncthreads();

    // ---- main loop: 2 i's per wave, 9 j-tiles each -------------------------
#pragma unroll
    for (int ii = 0; ii < 2; ++ii) {
        const int i = (blockIdx.y * 4 + wave) * 2 + ii;   // 0..143

        float gjA[8], gjB[8];
#pragma unroll
        for (int j = 0; j < 8; ++j) {
            gjA[j] = s_gjb[i * STR + h0 + j];
            gjB[j] = s_gjb[i * STR + 32 + h0 + j];
        }

        for (int jt = 0; jt < 9; ++jt) {
            const float* gr = &s_gi[(jt * 16 + m) * STR];

            bf16x8 A0, A1;
#pragma unroll
            for (int j = 0; j < 8; ++j) {
                float v0 = gr[h0 + j]      + gjA[j];
                float v1 = gr[32 + h0 + j] + gjB[j];
                A0[j] = (__bf16)leaky(v0);
                A1[j] = (__bf16)leaky(v1);
            }

            floatx4 Cf[4];
#pragma unroll
            for (int nt = 0; nt < 4; ++nt) {
                Cf[nt] = floatx4{0.f, 0.f, 0.f, 0.f};
                Cf[nt] = __builtin_amdgcn_mfma_f32_16x16x32_bf16(A0, Bf[0][nt], Cf[nt], 0, 0, 0);
                Cf[nt] = __builtin_amdgcn_mfma_f32_16x16x32_bf16(A1, Bf[1][nt], Cf[nt], 0, 0, 0);
            }

#pragma unroll
            for (int nt = 0; nt < 4; ++nt) {
#pragma unroll
                for (int r = 0; r < 4; ++r)
                    sacc[nt] += leaky(Cf[nt][r] + b2v[nt]);
            }
        }
    }

    // ---- reduce quad-groups in-wave, then block-reduce via LDS -------------
#pragma unroll
    for (int nt = 0; nt < 4; ++nt) {
        float s = sacc[nt];
        s += __shfl_xor(s, 16, 64);
        s += __shfl_xor(s, 32, 64);
        sacc[nt] = s;                     // valid in quad==0 lanes (m = col)
    }
    __syncthreads();                      // LDS reads of main loop done
    if (quad == 0) {
#pragma unroll
        for (int nt = 0; nt < 4; ++nt)
            smem[wave * STR + nt * 16 + m] = sacc[nt];
    }
    __syncthreads();
    if (t < HID_) {
        float s = smem[0 * STR + t] + smem[1 * STR + t]
                + smem[2 * STR + t] + smem[3 * STR + t];
        partial[(b * YB_ + blockIdx.y) * HID_ + t] = s;
    }
}

// ---------------- kernel 3: partial-reduce + final 64->64->64 MLP -----------
__global__ __launch_bounds__(64) void k_mlp(const float* __restrict__ partial,
                                            const float* __restrict__ Wp,
                                            const float* __restrict__ bp,
                                            const float* __restrict__ Wo,
                                            const float* __restrict__ bo,
                                            float* __restrict__ out)
{
    __shared__ float s0[HID_], s1[HID_];
    int b = blockIdx.x, k = threadIdx.x;

    float a = 0.f;
#pragma unroll
    for (int yb = 0; yb < YB_; ++yb)
        a += partial[(b * YB_ + yb) * HID_ + k];
    s0[k] = a;
    __syncthreads();

    float v = bp[k];
#pragma unroll 8
    for (int h = 0; h < HID_; ++h) v = fmaf(s0[h], Wp[h * HID_ + k], v);
    v = leaky(v);
    s1[k] = v;
    __syncthreads();
    float w = bo[k];
#pragma unroll 8
    for (int h = 0; h < HID_; ++h) w = fmaf(s1[h], Wo[h * HID_ + k], w);
    w = leaky(w);
    out[b * HID_ + k] = w;
}

// ---------------- launch ----------------------------------------------------
extern "C" void kernel_launch(void* const* d_in, const int* in_sizes, int n_in,
                              void* d_out, int out_size, void* d_ws, size_t ws_size,
                              hipStream_t stream)
{
    const float* x_img = (const float*)d_in[0];
    const float* W1    = (const float*)d_in[1];
    const float* b1    = (const float*)d_in[2];
    const float* W2    = (const float*)d_in[3];
    const float* b2    = (const float*)d_in[4];
    const float* Wp    = (const float*)d_in[5];
    const float* bp    = (const float*)d_in[6];
    const float* Wo    = (const float*)d_in[7];
    const float* bo    = (const float*)d_in[8];
    float* out = (float*)d_out;

    float* gi      = (float*)d_ws;                 // B*L*HID floats
    float* gj      = gi + B_ * L_ * HID_;
    float* partial = gj + B_ * L_ * HID_;          // B*YB_*HID floats

    k_proj <<<dim3(B_ * 36), 256, 0, stream>>>(x_img, W1, gi, gj);
    k_pairs<<<dim3(B_, YB_), 256, 0, stream>>>(gi, gj, b1, W2, b2, partial);
    k_mlp  <<<dim3(B_),       64, 0, stream>>>(partial, Wp, bp, Wo, bo, out);
}

// Round 4
// 111.992 us; speedup vs baseline: 1.9138x; 1.0206x over previous
//
#include <hip/hip_runtime.h>

// BatchRelationalModule: B=32, C=128, H=W=12 -> L=144, D=129, HID=64
// out[b,k] = MLP( sum_{i,j} leaky( leaky(gi[b,j,:]+gj[b,i,:]+b1) @ W2 + b2 )[k] )
//
// Round 4: k_pairs prologue/epilogue rewritten as float4 vector math so the
// compiler emits packed fp32 VALU (v_pk_add/mul/max_f32) and ds_read_b128.
// LDS row stride 65 -> 68 to keep 16B alignment for b128 reads.

#define B_   32
#define C_   128
#define L_   144
#define HID_ 64
#define D_   129
#define STR  68   // floats per LDS row: 16B-aligned rows, +4 skew breaks bank aliasing
#define YB_  18   // k_pairs grid.y (i-tiles of 8)

typedef __bf16 bf16x8 __attribute__((ext_vector_type(8)));
typedef float  floatx4 __attribute__((ext_vector_type(4)));

__device__ __forceinline__ float leaky(float x) { return fmaxf(x, 0.01f * x); }
__device__ __forceinline__ floatx4 leaky4(floatx4 x) {
    return __builtin_elementwise_max(x, x * 0.01f);
}

// ---------------- kernel 1: gi/gj projection --------------------------------
__global__ __launch_bounds__(256) void k_proj(const float* __restrict__ x_img,
                                              const float* __restrict__ W1,
                                              float* __restrict__ gi,
                                              float* __restrict__ gj)
{
    int t   = threadIdx.x;
    int h   = t & 63;
    int sub = t >> 6;
    int bid = blockIdx.x;             // 0 .. B_*36-1
    int b   = bid / 36;
    int l   = (bid % 36) * 4 + sub;

    const float* Wa = W1;             // rows 0..128
    const float* Wb = W1 + D_ * HID_; // rows 129..257
    const float* xp = x_img + (size_t)(b * C_) * L_ + l;

    float ai = 0.f, aj = 0.f;
#pragma unroll 4
    for (int c = 0; c < C_; ++c) {
        float xv = xp[c * L_];
        ai = fmaf(xv, Wa[c * HID_ + h], ai);
        aj = fmaf(xv, Wb[c * HID_ + h], aj);
    }
    float fl = (float)l;
    ai = fmaf(fl, Wa[C_ * HID_ + h], ai);
    aj = fmaf(fl, Wb[C_ * HID_ + h], aj);

    int o = (b * L_ + l) * HID_ + h;
    gi[o] = ai;
    gj[o] = aj;
}

// ---------------- kernel 2: pairwise core via MFMA --------------------------
// grid = (B_, YB_), 256 threads = 4 waves. Each wave: 2 i's x 9 j-tiles of 16.
// Writes partial[(b*YB_ + yb)*64 + k] -- no atomics, no pre-zeroing needed.
__global__ __launch_bounds__(256, 2) void k_pairs(const float* __restrict__ gi,
                                                  const float* __restrict__ gj,
                                                  const float* __restrict__ b1,
                                                  const float* __restrict__ W2,
                                                  const float* __restrict__ b2,
                                                  float* __restrict__ partial)
{
    __shared__ float smem[2 * L_ * STR];   // 78336 B -> 2 blocks/CU
    float* s_gi  = smem;
    float* s_gjb = smem + L_ * STR;

    const int t    = threadIdx.x;
    const int wave = t >> 6;
    const int lane = t & 63;
    const int m    = lane & 15;        // A row / C col index
    const int quad = lane >> 4;        // k-subchunk selector
    const int b    = blockIdx.x;

    // ---- stage gi and gj(+b1) into LDS; float4 both sides ------------------
    {
        const floatx4* g4i = (const floatx4*)(gi + (size_t)b * (L_ * HID_));
        const floatx4* g4j = (const floatx4*)(gj + (size_t)b * (L_ * HID_));
        const floatx4* b14 = (const floatx4*)b1;
        for (int idx = t; idx < L_ * HID_ / 4; idx += 256) {
            int l  = idx >> 4;             // 16 float4 per row
            int c4 = idx & 15;
            floatx4 vi = g4i[idx];
            floatx4 vj = g4j[idx] + b14[c4];
            *(floatx4*)&s_gi [l * STR + c4 * 4] = vi;
            *(floatx4*)&s_gjb[l * STR + c4 * 4] = vj;
        }
    }

    // ---- W2 -> B-fragments in registers (once per wave) --------------------
    bf16x8 Bf[2][4];
#pragma unroll
    for (int kc = 0; kc < 2; ++kc)
#pragma unroll
        for (int nt = 0; nt < 4; ++nt)
#pragma unroll
            for (int j = 0; j < 8; ++j)
                Bf[kc][nt][j] = (__bf16)W2[(kc * 32 + quad * 8 + j) * HID_ + nt * 16 + m];

    float b2v[4];
#pragma unroll
    for (int nt = 0; nt < 4; ++nt) b2v[nt] = b2[nt * 16 + m];

    floatx4 sacc[4];
#pragma unroll
    for (int nt = 0; nt < 4; ++nt) sacc[nt] = floatx4{0.f, 0.f, 0.f, 0.f};

    const int h0 = quad * 8;

    __syncthreads();

    // ---- main loop: 2 i's per wave, 9 j-tiles each -------------------------
#pragma unroll
    for (int ii = 0; ii < 2; ++ii) {
        const int i = (blockIdx.y * 4 + wave) * 2 + ii;   // 0..143

        const float* hr = &s_gjb[i * STR];
        floatx4 gjA0 = *(const floatx4*)(hr + h0);
        floatx4 gjA1 = *(const floatx4*)(hr + h0 + 4);
        floatx4 gjB0 = *(const floatx4*)(hr + 32 + h0);
        floatx4 gjB1 = *(const floatx4*)(hr + 32 + h0 + 4);

        for (int jt = 0; jt < 9; ++jt) {
            const float* gr = &s_gi[(jt * 16 + m) * STR];

            floatx4 va0 = *(const floatx4*)(gr + h0)          + gjA0;
            floatx4 va1 = *(const floatx4*)(gr + h0 + 4)      + gjA1;
            floatx4 vb0 = *(const floatx4*)(gr + 32 + h0)     + gjB0;
            floatx4 vb1 = *(const floatx4*)(gr + 32 + h0 + 4) + gjB1;
            va0 = leaky4(va0); va1 = leaky4(va1);
            vb0 = leaky4(vb0); vb1 = leaky4(vb1);

            bf16x8 A0, A1;
#pragma unroll
            for (int j = 0; j < 4; ++j) {
                A0[j]     = (__bf16)va0[j];
                A0[4 + j] = (__bf16)va1[j];
                A1[j]     = (__bf16)vb0[j];
                A1[4 + j] = (__bf16)vb1[j];
            }

            floatx4 Cf[4];
#pragma unroll
            for (int nt = 0; nt < 4; ++nt) {
                Cf[nt] = floatx4{0.f, 0.f, 0.f, 0.f};
                Cf[nt] = __builtin_amdgcn_mfma_f32_16x16x32_bf16(A0, Bf[0][nt], Cf[nt], 0, 0, 0);
                Cf[nt] = __builtin_amdgcn_mfma_f32_16x16x32_bf16(A1, Bf[1][nt], Cf[nt], 0, 0, 0);
            }

            // epilogue: leaky(C + b2) accumulated; all 4 regs share n = nt*16+m
#pragma unroll
            for (int nt = 0; nt < 4; ++nt)
                sacc[nt] += leaky4(Cf[nt] + b2v[nt]);
        }
    }

    // ---- reduce quad-groups in-wave, then block-reduce via LDS -------------
    float red[4];
#pragma unroll
    for (int nt = 0; nt < 4; ++nt) {
        float s = sacc[nt][0] + sacc[nt][1] + sacc[nt][2] + sacc[nt][3];
        s += __shfl_xor(s, 16, 64);
        s += __shfl_xor(s, 32, 64);
        red[nt] = s;                      // valid in quad==0 lanes (m = col)
    }
    __syncthreads();                      // LDS reads of main loop done
    if (quad == 0) {
#pragma unroll
        for (int nt = 0; nt < 4; ++nt)
            smem[wave * STR + nt * 16 + m] = red[nt];
    }
    __syncthreads();
    if (t < HID_) {
        float s = smem[0 * STR + t] + smem[1 * STR + t]
                + smem[2 * STR + t] + smem[3 * STR + t];
        partial[(b * YB_ + blockIdx.y) * HID_ + t] = s;
    }
}

// ---------------- kernel 3: partial-reduce + final 64->64->64 MLP -----------
__global__ __launch_bounds__(64) void k_mlp(const float* __restrict__ partial,
                                            const float* __restrict__ Wp,
                                            const float* __restrict__ bp,
                                            const float* __restrict__ Wo,
                                            const float* __restrict__ bo,
                                            float* __restrict__ out)
{
    __shared__ float s0[HID_], s1[HID_];
    int b = blockIdx.x, k = threadIdx.x;

    float a = 0.f;
#pragma unroll
    for (int yb = 0; yb < YB_; ++yb)
        a += partial[(b * YB_ + yb) * HID_ + k];
    s0[k] = a;
    __syncthreads();

    float v = bp[k];
#pragma unroll 8
    for (int h = 0; h < HID_; ++h) v = fmaf(s0[h], Wp[h * HID_ + k], v);
    v = leaky(v);
    s1[k] = v;
    __syncthreads();
    float w = bo[k];
#pragma unroll 8
    for (int h = 0; h < HID_; ++h) w = fmaf(s1[h], Wo[h * HID_ + k], w);
    w = leaky(w);
    out[b * HID_ + k] = w;
}

// ---------------- launch ----------------------------------------------------
extern "C" void kernel_launch(void* const* d_in, const int* in_sizes, int n_in,
                              void* d_out, int out_size, void* d_ws, size_t ws_size,
                              hipStream_t stream)
{
    const float* x_img = (const float*)d_in[0];
    const float* W1    = (const float*)d_in[1];
    const float* b1    = (const float*)d_in[2];
    const float* W2    = (const float*)d_in[3];
    const float* b2    = (const float*)d_in[4];
    const float* Wp    = (const float*)d_in[5];
    const float* bp    = (const float*)d_in[6];
    const float* Wo    = (const float*)d_in[7];
    const float* bo    = (const float*)d_in[8];
    float* out = (float*)d_out;

    float* gi      = (float*)d_ws;                 // B*L*HID floats
    float* gj      = gi + B_ * L_ * HID_;
    float* partial = gj + B_ * L_ * HID_;          // B*YB_*HID floats

    k_proj <<<dim3(B_ * 36), 256, 0, stream>>>(x_img, W1, gi, gj);
    k_pairs<<<dim3(B_, YB_), 256, 0, stream>>>(gi, gj, b1, W2, b2, partial);
    k_mlp  <<<dim3(B_),       64, 0, stream>>>(partial, Wp, bp, Wo, bo, out);
}

// Round 5
// 106.111 us; speedup vs baseline: 2.0199x; 1.0554x over previous
//
#include <hip/hip_runtime.h>

// BatchRelationalModule: B=32, C=128, H=W=12 -> L=144, D=129, HID=64
// out[b,k] = MLP( sum_{i,j} leaky( leaky(gi[b,j,:]+gj[b,i,:]+b1) @ W2 + b2 )[k] )
//
// Round 5:
//  - k_proj v2: W1-half staged in LDS (33 KB), grid (64,12); b1 folded into gjb.
//  - k_pairs v3: only s_gi in LDS (39 KB -> 4 blocks/CU, no tail); each wave
//    loads its 2 gjb rows directly from global (broadcast dwordx4).
//  - A-build math bitwise-identical to round 4 (absmax should stay 128).

#define B_   32
#define C_   128
#define L_   144
#define HID_ 64
#define D_   129
#define STR  68   // floats per LDS row: 16B-aligned, +4 skew -> <=2-way banks (free)
#define YB_  18   // k_pairs grid.y (i-tiles of 8)
#define PL_  12   // k_proj l's per block

typedef __bf16 bf16x8 __attribute__((ext_vector_type(8)));
typedef float  floatx4 __attribute__((ext_vector_type(4)));

__device__ __forceinline__ float leaky(float x) { return fmaxf(x, 0.01f * x); }
__device__ __forceinline__ floatx4 leaky4(floatx4 x) {
    return __builtin_elementwise_max(x, x * 0.01f);
}

// ---------------- kernel 1: gi / gjb projection (W-half in LDS) -------------
// grid = (B_*2, L_/PL_): x = b*2 + which (0: gi, 1: gjb=gj+b1), y = l-tile.
__global__ __launch_bounds__(256) void k_proj(const float* __restrict__ x_img,
                                              const float* __restrict__ W1,
                                              const float* __restrict__ b1,
                                              float* __restrict__ gi,
                                              float* __restrict__ gjb)
{
    __shared__ float sW[D_ * HID_];            // 33024 B -> 4 blocks/CU
    const int t     = threadIdx.x;
    const int b     = blockIdx.x >> 1;
    const int which = blockIdx.x & 1;
    const int l0    = blockIdx.y * PL_;

    // stage this block's W1 half (129 x 64 fp32)
    {
        const floatx4* w4 = (const floatx4*)(W1 + which * (D_ * HID_));
        floatx4* s4 = (floatx4*)sW;
        for (int idx = t; idx < D_ * HID_ / 4; idx += 256)   // 2064 float4
            s4[idx] = w4[idx];
    }
    __syncthreads();

    const int h    = t & 63;
    const int wave = t >> 6;
    float* outp  = which ? gjb : gi;
    const float bias = which ? b1[h] : 0.f;

#pragma unroll
    for (int il = 0; il < PL_ / 4; ++il) {     // 3 l's per wave
        const int l = l0 + wave * (PL_ / 4) + il;
        const float* xp = x_img + (size_t)(b * C_) * L_ + l;

        // two partial accumulators to break the fma dependency chain
        float a0 = fmaf((float)l, sW[C_ * HID_ + h], bias);
        float a1 = 0.f;
#pragma unroll 4
        for (int c = 0; c < C_; c += 2) {
            a0 = fmaf(xp[c * L_],       sW[c * HID_ + h],       a0);
            a1 = fmaf(xp[(c + 1) * L_], sW[(c + 1) * HID_ + h], a1);
        }
        outp[(b * L_ + l) * HID_ + h] = a0 + a1;
    }
}

// ---------------- kernel 2: pairwise core via MFMA --------------------------
// grid = (B_, YB_), 256 threads = 4 waves. Each wave: 2 i's x 9 j-tiles of 16.
// Writes partial[(b*YB_ + yb)*64 + k] -- no atomics, no pre-zeroing needed.
__global__ __launch_bounds__(256, 4) void k_pairs(const float* __restrict__ gi,
                                                  const float* __restrict__ gjb,
                                                  const float* __restrict__ W2,
                                                  const float* __restrict__ b2,
                                                  float* __restrict__ partial)
{
    __shared__ float s_gi[L_ * STR];           // 39168 B -> 4 blocks/CU

    const int t    = threadIdx.x;
    const int wave = t >> 6;
    const int lane = t & 63;
    const int m    = lane & 15;        // A row / C col index
    const int quad = lane >> 4;        // k-subchunk selector
    const int b    = blockIdx.x;

    // ---- stage gi b-slice into LDS; float4 both sides ----------------------
    {
        const floatx4* g4i = (const floatx4*)(gi + (size_t)b * (L_ * HID_));
        for (int idx = t; idx < L_ * HID_ / 4; idx += 256) {  // 2304 float4
            int l  = idx >> 4;             // 16 float4 per row
            int c4 = idx & 15;
            *(floatx4*)&s_gi[l * STR + c4 * 4] = g4i[idx];
        }
    }

    // ---- W2 -> B-fragments in registers (once per wave) --------------------
    bf16x8 Bf[2][4];
#pragma unroll
    for (int kc = 0; kc < 2; ++kc)
#pragma unroll
        for (int nt = 0; nt < 4; ++nt)
#pragma unroll
            for (int j = 0; j < 8; ++j)
                Bf[kc][nt][j] = (__bf16)W2[(kc * 32 + quad * 8 + j) * HID_ + nt * 16 + m];

    float b2v[4];
#pragma unroll
    for (int nt = 0; nt < 4; ++nt) b2v[nt] = b2[nt * 16 + m];

    floatx4 sacc[4];
#pragma unroll
    for (int nt = 0; nt < 4; ++nt) sacc[nt] = floatx4{0.f, 0.f, 0.f, 0.f};

    const int h0 = quad * 8;

    __syncthreads();

    // ---- main loop: 2 i's per wave, 9 j-tiles each -------------------------
#pragma unroll
    for (int ii = 0; ii < 2; ++ii) {
        const int i = (blockIdx.y * 4 + wave) * 2 + ii;   // 0..143

        // this wave's gjb row, straight from global (L2-resident, broadcast)
        const float* gjr = gjb + ((size_t)b * L_ + i) * HID_;
        floatx4 gjA0 = *(const floatx4*)(gjr + h0);
        floatx4 gjA1 = *(const floatx4*)(gjr + h0 + 4);
        floatx4 gjB0 = *(const floatx4*)(gjr + 32 + h0);
        floatx4 gjB1 = *(const floatx4*)(gjr + 32 + h0 + 4);

        for (int jt = 0; jt < 9; ++jt) {
            const float* gr = &s_gi[(jt * 16 + m) * STR];

            floatx4 va0 = *(const floatx4*)(gr + h0)          + gjA0;
            floatx4 va1 = *(const floatx4*)(gr + h0 + 4)      + gjA1;
            floatx4 vb0 = *(const floatx4*)(gr + 32 + h0)     + gjB0;
            floatx4 vb1 = *(const floatx4*)(gr + 32 + h0 + 4) + gjB1;
            va0 = leaky4(va0); va1 = leaky4(va1);
            vb0 = leaky4(vb0); vb1 = leaky4(vb1);

            bf16x8 A0, A1;
#pragma unroll
            for (int j = 0; j < 4; ++j) {
                A0[j]     = (__bf16)va0[j];
                A0[4 + j] = (__bf16)va1[j];
                A1[j]     = (__bf16)vb0[j];
                A1[4 + j] = (__bf16)vb1[j];
            }

            floatx4 Cf[4];
#pragma unroll
            for (int nt = 0; nt < 4; ++nt) {
                Cf[nt] = floatx4{0.f, 0.f, 0.f, 0.f};
                Cf[nt] = __builtin_amdgcn_mfma_f32_16x16x32_bf16(A0, Bf[0][nt], Cf[nt], 0, 0, 0);
                Cf[nt] = __builtin_amdgcn_mfma_f32_16x16x32_bf16(A1, Bf[1][nt], Cf[nt], 0, 0, 0);
            }

#pragma unroll
            for (int nt = 0; nt < 4; ++nt)
                sacc[nt] += leaky4(Cf[nt] + b2v[nt]);
        }
    }

    // ---- reduce quad-groups in-wave, then block-reduce via LDS -------------
    float red[4];
#pragma unroll
    for (int nt = 0; nt < 4; ++nt) {
        float s = sacc[nt][0] + sacc[nt][1] + sacc[nt][2] + sacc[nt][3];
        s += __shfl_xor(s, 16, 64);
        s += __shfl_xor(s, 32, 64);
        red[nt] = s;                      // valid in quad==0 lanes (m = col)
    }
    __syncthreads();                      // LDS reads of main loop done
    if (quad == 0) {
#pragma unroll
        for (int nt = 0; nt < 4; ++nt)
            s_gi[wave * STR + nt * 16 + m] = red[nt];
    }
    __syncthreads();
    if (t < HID_) {
        float s = s_gi[0 * STR + t] + s_gi[1 * STR + t]
                + s_gi[2 * STR + t] + s_gi[3 * STR + t];
        partial[(b * YB_ + blockIdx.y) * HID_ + t] = s;
    }
}

// ---------------- kernel 3: partial-reduce + final 64->64->64 MLP -----------
__global__ __launch_bounds__(64) void k_mlp(const float* __restrict__ partial,
                                            const float* __restrict__ Wp,
                                            const float* __restrict__ bp,
                                            const float* __restrict__ Wo,
                                            const float* __restrict__ bo,
                                            float* __restrict__ out)
{
    __shared__ float s0[HID_], s1[HID_];
    int b = blockIdx.x, k = threadIdx.x;

    float a = 0.f;
#pragma unroll
    for (int yb = 0; yb < YB_; ++yb)
        a += partial[(b * YB_ + yb) * HID_ + k];
    s0[k] = a;
    __syncthreads();

    float v = bp[k];
#pragma unroll 8
    for (int h = 0; h < HID_; ++h) v = fmaf(s0[h], Wp[h * HID_ + k], v);
    v = leaky(v);
    s1[k] = v;
    __syncthreads();
    float w = bo[k];
#pragma unroll 8
    for (int h = 0; h < HID_; ++h) w = fmaf(s1[h], Wo[h * HID_ + k], w);
    w = leaky(w);
    out[b * HID_ + k] = w;
}

// ---------------- launch ----------------------------------------------------
extern "C" void kernel_launch(void* const* d_in, const int* in_sizes, int n_in,
                              void* d_out, int out_size, void* d_ws, size_t ws_size,
                              hipStream_t stream)
{
    const float* x_img = (const float*)d_in[0];
    const float* W1    = (const float*)d_in[1];
    const float* b1    = (const float*)d_in[2];
    const float* W2    = (const float*)d_in[3];
    const float* b2    = (const float*)d_in[4];
    const float* Wp    = (const float*)d_in[5];
    const float* bp    = (const float*)d_in[6];
    const float* Wo    = (const float*)d_in[7];
    const float* bo    = (const float*)d_in[8];
    float* out = (float*)d_out;

    float* gi      = (float*)d_ws;                 // B*L*HID floats
    float* gjb     = gi + B_ * L_ * HID_;          // gj + b1, B*L*HID floats
    float* partial = gjb + B_ * L_ * HID_;         // B*YB_*HID floats

    k_proj <<<dim3(B_ * 2, L_ / PL_), 256, 0, stream>>>(x_img, W1, b1, gi, gjb);
    k_pairs<<<dim3(B_, YB_),          256, 0, stream>>>(gi, gjb, W2, b2, partial);
    k_mlp  <<<dim3(B_),                64, 0, stream>>>(partial, Wp, bp, Wo, bo, out);
}